// Round 4
// baseline (47.233 us; speedup 1.0000x reference)
//
#include <hip/hip_runtime.h>

#define N 4096
#define MASK 4095

// 32-lane butterfly sum (masks 1..16 -> ds_swizzle): every lane in each
// 32-lane group ends with the group total.
__device__ __forceinline__ float red32(float v) {
    v += __shfl_xor(v, 1, 64);
    v += __shfl_xor(v, 2, 64);
    v += __shfl_xor(v, 4, 64);
    v += __shfl_xor(v, 8, 64);
    v += __shfl_xor(v, 16, 64);
    return v;
}

// Merge-tree reduction used by K3 (4 independent 64-lane sums, 7 shuffles).
// Result mapping: lane-group sg = lane>>4: sg0->g0, sg1->g2, sg2->g1, sg3->g3.
__device__ __forceinline__ float fold(float u, float v, int m) {
    const bool hi = (threadIdx.x & m) != 0;
    const float t = hi ? u : v;
    const float s = __shfl_xor(t, m, 64);
    return (hi ? v : u) + s;
}

__device__ __forceinline__ float greduce4(float g0, float g1, float g2, float g3) {
    float c1 = fold(g0, g1, 32);
    float c2 = fold(g2, g3, 32);
    float e  = fold(c1, c2, 16);
    e += __shfl_xor(e, 8, 64);
    e += __shfl_xor(e, 4, 64);
    e += __shfl_xor(e, 2, 64);
    e += __shfl_xor(e, 1, 64);
    return e;
}

// ---------------------------------------------------------------------------
// K1: fused single pass over km1 and km2.
//   256 blocks x 1024 threads (1 block/CU, 16 waves). Block owns 16 whole
//   rows; thread t owns cols 4t..4t+3 (one float4 per row per matrix).
//   4-row double-buffered batches: 8 x 1KB wave-loads always in flight,
//   whole 16KB rows fetched as contiguous bursts.
//   d-reduce: 5-step shfl_xor butterfly -> dpart[j][32] (K2-compatible).
//   t-accumulate: 4 cols/thread over 16 rows -> tpart[b][4096].
// ---------------------------------------------------------------------------
__global__ __launch_bounds__(1024, 4) void k1_fused(
    const float* __restrict__ key,
    const float* __restrict__ km1, const float* __restrict__ km2,
    const float* __restrict__ o1, const float* __restrict__ o2,
    float* __restrict__ tpart1, float* __restrict__ tpart2,
    float* __restrict__ dpart1, float* __restrict__ dpart2)
{
    __shared__ float skey[4096 + 128];
    const int t = threadIdx.x;
    const int b = blockIdx.x;
    const int j0 = b * 16;

    #pragma unroll
    for (int q = 0; q < 4; ++q) {
        const int idx = q * 1024 + t;
        skey[idx + (idx >> 5)] = key[idx];
    }
    __syncthreads();

    // key window in regs: w[i] = key[(4t - j0 - 15 + i) & 4095], i = 0..18
    // row j0+r, col 4t+cx  ->  w[cx + 15 - r]
    float w[19];
    #pragma unroll
    for (int i = 0; i < 19; ++i) {
        const int idx = (4 * t - j0 - 15 + i) & MASK;
        w[i] = skey[idx + (idx >> 5)];
    }

    const float4* q1 = (const float4*)km1 + (size_t)j0 * 1024 + t;
    const float4* q2 = (const float4*)km2 + (size_t)j0 * 1024 + t;

    float4 A[2][4], B[2][4];
    #pragma unroll
    for (int i = 0; i < 4; ++i) A[0][i] = q1[(size_t)i * 1024];
    #pragma unroll
    for (int i = 0; i < 4; ++i) B[0][i] = q2[(size_t)i * 1024];

    float tp1[4] = {0.f, 0.f, 0.f, 0.f};
    float tp2[4] = {0.f, 0.f, 0.f, 0.f};

    #pragma unroll
    for (int rb = 0; rb < 4; ++rb) {
        const int cur = rb & 1, nxt = cur ^ 1;
        if (rb < 3) {
            #pragma unroll
            for (int i = 0; i < 4; ++i) A[nxt][i] = q1[(size_t)((rb + 1) * 4 + i) * 1024];
            #pragma unroll
            for (int i = 0; i < 4; ++i) B[nxt][i] = q2[(size_t)((rb + 1) * 4 + i) * 1024];
        }
        #pragma unroll
        for (int rr = 0; rr < 4; ++rr) {
            const int r = rb * 4 + rr;
            const float4 a = A[cur][rr];
            const float4 v = B[cur][rr];
            const float oa = o1[j0 + r], ob = o2[j0 + r];
            tp1[0] += oa * a.x; tp1[1] += oa * a.y; tp1[2] += oa * a.z; tp1[3] += oa * a.w;
            tp2[0] += ob * v.x; tp2[1] += ob * v.y; tp2[2] += ob * v.z; tp2[3] += ob * v.w;
            float dp1 = w[15 - r] * a.x + w[16 - r] * a.y + w[17 - r] * a.z + w[18 - r] * a.w;
            float dp2 = w[15 - r] * v.x + w[16 - r] * v.y + w[17 - r] * v.z + w[18 - r] * v.w;
            dp1 = red32(dp1);
            dp2 = red32(dp2);
            if ((t & 31) == 0) {
                dpart1[(size_t)(j0 + r) * 32 + (t >> 5)] = dp1;
                dpart2[(size_t)(j0 + r) * 32 + (t >> 5)] = dp2;
            }
        }
    }

    ((float4*)(tpart1 + (size_t)b * N))[t] = make_float4(tp1[0], tp1[1], tp1[2], tp1[3]);
    ((float4*)(tpart2 + (size_t)b * N))[t] = make_float4(tp2[0], tp2[1], tp2[2], tp2[3]);
}

// ---------------------------------------------------------------------------
// K2: reduce partials. grid = 1280 x 256. (unchanged)
// ---------------------------------------------------------------------------
__global__ __launch_bounds__(256) void k2_reduce(
    const float* __restrict__ tpart1, const float* __restrict__ tpart2,
    const float* __restrict__ dpart1, const float* __restrict__ dpart2,
    float* __restrict__ t1, float* __restrict__ t2,
    float* __restrict__ d1, float* __restrict__ d2)
{
    __shared__ float sdata[256];
    const int b = blockIdx.x;
    const int t = threadIdx.x;

    if (b < 256) {
        const float* src = (b < 128) ? tpart1 : tpart2;
        float* dst       = (b < 128) ? t1 : t2;
        const int colbase = (b & 127) * 32;
        const int col = t & 31;
        const int sg = t >> 5;
        float a0 = 0.f, a1 = 0.f, a2 = 0.f, a3 = 0.f;
        #pragma unroll 4
        for (int k = 0; k < 32; k += 4) {
            a0 += src[(size_t)(sg + 8 * (k + 0)) * N + colbase + col];
            a1 += src[(size_t)(sg + 8 * (k + 1)) * N + colbase + col];
            a2 += src[(size_t)(sg + 8 * (k + 2)) * N + colbase + col];
            a3 += src[(size_t)(sg + 8 * (k + 3)) * N + colbase + col];
        }
        sdata[t] = (a0 + a1) + (a2 + a3);
        __syncthreads();
        if (t < 32) {
            float s = 0.f;
            #pragma unroll
            for (int i = 0; i < 8; ++i) s += sdata[i * 32 + t];
            dst[colbase + t] = s;
        }
    } else {
        const int db = b - 256;
        const float* src = (db < 512) ? dpart1 : dpart2;
        float* dst       = (db < 512) ? d1 : d2;
        const int rowbase = (db & 511) * 8;
        const int row = rowbase + (t >> 5);
        const int s = t & 31;
        float v = src[(size_t)row * 32 + s];
        #pragma unroll
        for (int off = 16; off > 0; off >>= 1) v += __shfl_down(v, off, 32);
        if (s == 0) dst[row] = v;
    }
}

// ---------------------------------------------------------------------------
// K3: three circulant matvecs + final combine. 1024 blocks x 4 rows each.
// ---------------------------------------------------------------------------
__global__ __launch_bounds__(256) void k3_final(
    const float* __restrict__ key, const float* __restrict__ x,
    const float* __restrict__ t1, const float* __restrict__ t2,
    const float* __restrict__ d1, const float* __restrict__ d2,
    const float* __restrict__ o1, const float* __restrict__ o2,
    float* __restrict__ out)
{
    __shared__ float skey[4096 + 128];
    __shared__ float sred[48];                 // [wave][v][row]
    const int t = threadIdx.x;
    const int j0 = blockIdx.x * 4;

    #pragma unroll
    for (int q = 0; q < 16; ++q) {
        const int idx = q * 256 + t;
        skey[idx + (idx >> 5)] = key[idx];
    }
    __syncthreads();

    float acc[4][3];
    #pragma unroll
    for (int r = 0; r < 4; ++r)
        #pragma unroll
        for (int v = 0; v < 3; ++v) acc[r][v] = 0.f;

    #pragma unroll
    for (int q = 0; q < 4; ++q) {
        const int k0 = q * 1024 + 4 * t;
        const float4 xv = *(const float4*)(x + k0);
        const float4 u1 = *(const float4*)(t1 + k0);
        const float4 u2 = *(const float4*)(t2 + k0);
        float kw[7];                           // (k0 + c - j0 - r), c:0..3, r:0..3
        #pragma unroll
        for (int i = 0; i < 7; ++i) {
            const int widx = (k0 - j0 - 3 + i) & MASK;
            kw[i] = skey[widx + (widx >> 5)];
        }
        #pragma unroll
        for (int r = 0; r < 4; ++r) {
            const float kv0 = kw[3 - r], kv1 = kw[4 - r], kv2 = kw[5 - r], kv3 = kw[6 - r];
            acc[r][0] += kv0 * xv.x + kv1 * xv.y + kv2 * xv.z + kv3 * xv.w;
            acc[r][1] += kv0 * u1.x + kv1 * u1.y + kv2 * u1.z + kv3 * u1.w;
            acc[r][2] += kv0 * u2.x + kv1 * u2.y + kv2 * u2.z + kv3 * u2.w;
        }
    }

    float rv[3];
    #pragma unroll
    for (int v = 0; v < 3; ++v)
        rv[v] = greduce4(acc[0][v], acc[1][v], acc[2][v], acc[3][v]);

    const int lane = t & 63, wave = t >> 6, sg = lane >> 4;
    const int off = (0x3120 >> (sg * 4)) & 0xF;  // which row this lane holds
    if ((lane & 15) == 0) {
        #pragma unroll
        for (int v = 0; v < 3; ++v) sred[wave * 12 + v * 4 + off] = rv[v];
    }
    __syncthreads();

    if (t < 4) {
        const int j = j0 + t;
        float vb = 0.f, v1 = 0.f, v2 = 0.f;
        #pragma unroll
        for (int wv = 0; wv < 4; ++wv) {
            vb += sred[wv * 12 + 0 + t];
            v1 += sred[wv * 12 + 4 + t];
            v2 += sred[wv * 12 + 8 + t];
        }
        const float dd1 = d1[j], dd2 = d2[j];
        const float r2 = v1 - dd1 * o1[j];
        const float r4 = v2 - dd2 * o2[j];
        out[j] = (vb - r2 - r4) / dd1;
        if (j == N - 1) out[N] = dd2;          // redun3 = d2[last row]
    }
}

extern "C" void kernel_launch(void* const* d_in, const int* in_sizes, int n_in,
                              void* d_out, int out_size, void* d_ws, size_t ws_size,
                              hipStream_t stream) {
    const float* key = (const float*)d_in[0];
    const float* x   = (const float*)d_in[1];
    const float* km1 = (const float*)d_in[2];
    const float* o1  = (const float*)d_in[3];
    const float* km2 = (const float*)d_in[4];
    const float* o2  = (const float*)d_in[5];
    float* out = (float*)d_out;

    float* ws = (float*)d_ws;
    float* tpart1 = ws;                                  // 256*4096
    float* tpart2 = tpart1 + (size_t)256 * N;            // 256*4096
    float* dpart1 = tpart2 + (size_t)256 * N;            // 4096*32
    float* dpart2 = dpart1 + (size_t)N * 32;             // 4096*32
    float* t1     = dpart2 + (size_t)N * 32;             // 4096
    float* t2     = t1 + N;
    float* d1     = t2 + N;
    float* d2     = d1 + N;

    hipLaunchKernelGGL(k1_fused, dim3(256), dim3(1024), 0, stream,
                       key, km1, km2, o1, o2, tpart1, tpart2, dpart1, dpart2);
    hipLaunchKernelGGL(k2_reduce, dim3(1280), dim3(256), 0, stream,
                       tpart1, tpart2, dpart1, dpart2, t1, t2, d1, d2);
    hipLaunchKernelGGL(k3_final, dim3(1024), dim3(256), 0, stream,
                       key, x, t1, t2, d1, d2, o1, o2, out);
}